// Round 8
// baseline (139.933 us; speedup 1.0000x reference)
//
#include <hip/hip_runtime.h>

typedef __attribute__((ext_vector_type(8))) short bf16x8;
typedef __attribute__((ext_vector_type(4))) float f32x4;

#define N 8192
#define FIN 512
#define FOUT 64
#define JSPLIT 8
#define JSPAN 1024       // j per block
#define PACKROW 260      // dwords per bitmap row (256 + 4 pad)

// round-to-nearest-even f32 -> bf16
static __device__ __forceinline__ short f2bf(float x) {
    unsigned u = __float_as_uint(x);
    u += 0x7FFFu + ((u >> 16) & 1u);
    return (short)(u >> 16);
}

// p = bit k of tc ? exp(leakyrelu(s,0.2)) : 0
static __device__ __forceinline__ float pbit(unsigned tc, int k, float s) {
    float p = __expf(fmaxf(s, 0.2f * s));
    return ((tc >> k) & 1u) ? p : 0.f;
}

// ---- Streaming probe + bitmap builder -------------------------------------
// Each wave task = one (row, 2048-j chunk): 8 x int4/lane = 8 KB contiguous
// reads in flight, ballot-packs 0/1 ints to bits, one coalesced 256-B store.
// Bit layout: dword index in row = (j>>7)*4 + (j&3); bit b within dword:
// j = (dword_chunk j-base) + 4*b + c.  (lane l accumulates it=l>>3,
// half=(l>>2)&1, c=l&3; store index ch*64+l matches exactly.)
__global__ __launch_bounds__(256) void gat_pack(const int* __restrict__ adj,
                                                unsigned* __restrict__ bm)
{
    const int w = threadIdx.x >> 6, l = threadIdx.x & 63;
    const int ntask = N * 4;
    const int stride = gridDim.x * 4;
    for (int task = blockIdx.x * 4 + w; task < ntask; task += stride) {
        const int row = task >> 2, ch = task & 3;
        const int* src = adj + (size_t)row * N + ch * 2048;
        int4 v[8];
        #pragma unroll
        for (int it = 0; it < 8; ++it)
            v[it] = *(const int4*)(src + it * 256 + l * 4);
        unsigned my = 0;
        #pragma unroll
        for (int it = 0; it < 8; ++it) {
            unsigned long long m0 = __ballot(v[it].x > 0);
            unsigned long long m1 = __ballot(v[it].y > 0);
            unsigned long long m2 = __ballot(v[it].z > 0);
            unsigned long long m3 = __ballot(v[it].w > 0);
            const int c = l & 3;
            unsigned long long mc = (c == 0) ? m0 : (c == 1) ? m1 : (c == 2) ? m2 : m3;
            unsigned part = (l & 4) ? (unsigned)(mc >> 32) : (unsigned)mc;
            my = ((l >> 3) == it) ? part : my;
        }
        bm[(size_t)row * PACKROW + ch * 64 + l] = my;
    }
}

// ---- Pass A: Wh = h@W; Bp = MFMA-B fragments; fsrc/fdst ----
// Bp[((jstep*4 + m)*64 + (g*16+c))*8 + e] = bf16(Wh[jstep*32+g*8+e][m*16+c])
__global__ __launch_bounds__(256) void gat_prep(const float* __restrict__ h,
    const float* __restrict__ W, const float* __restrict__ a,
    short* __restrict__ Bp, float* __restrict__ fsrc, float* __restrict__ fdst)
{
    __shared__ float lds[FOUT][16];
    const int i0 = blockIdx.x * 16;
    const int w = threadIdx.x >> 6, f = threadIdx.x & 63;
    const int ir = i0 + w * 4;
    const float* h0 = h + (size_t)ir * FIN;
    float acc0 = 0.f, acc1 = 0.f, acc2 = 0.f, acc3 = 0.f;
    for (int k = 0; k < FIN; k += 4) {
        float wv0 = W[(k + 0) * FOUT + f];
        float wv1 = W[(k + 1) * FOUT + f];
        float wv2 = W[(k + 2) * FOUT + f];
        float wv3 = W[(k + 3) * FOUT + f];
        float4 h0v = *(const float4*)(h0 + k);
        float4 h1v = *(const float4*)(h0 + FIN + k);
        float4 h2v = *(const float4*)(h0 + 2 * FIN + k);
        float4 h3v = *(const float4*)(h0 + 3 * FIN + k);
        acc0 = fmaf(h0v.w, wv3, fmaf(h0v.z, wv2, fmaf(h0v.y, wv1, fmaf(h0v.x, wv0, acc0))));
        acc1 = fmaf(h1v.w, wv3, fmaf(h1v.z, wv2, fmaf(h1v.y, wv1, fmaf(h1v.x, wv0, acc1))));
        acc2 = fmaf(h2v.w, wv3, fmaf(h2v.z, wv2, fmaf(h2v.y, wv1, fmaf(h2v.x, wv0, acc2))));
        acc3 = fmaf(h3v.w, wv3, fmaf(h3v.z, wv2, fmaf(h3v.y, wv1, fmaf(h3v.x, wv0, acc3))));
    }
    const float as = a[f], ad = a[FOUT + f];
    float s0 = acc0 * as, s1 = acc1 * as, s2 = acc2 * as, s3 = acc3 * as;
    float d0 = acc0 * ad, d1 = acc1 * ad, d2 = acc2 * ad, d3 = acc3 * ad;
    #pragma unroll
    for (int m = 1; m < 64; m <<= 1) {
        s0 += __shfl_xor(s0, m); s1 += __shfl_xor(s1, m);
        s2 += __shfl_xor(s2, m); s3 += __shfl_xor(s3, m);
        d0 += __shfl_xor(d0, m); d1 += __shfl_xor(d1, m);
        d2 += __shfl_xor(d2, m); d3 += __shfl_xor(d3, m);
    }
    if (f == 0) {
        fsrc[ir + 0] = s0; fsrc[ir + 1] = s1; fsrc[ir + 2] = s2; fsrc[ir + 3] = s3;
        fdst[ir + 0] = d0; fdst[ir + 1] = d1; fdst[ir + 2] = d2; fdst[ir + 3] = d3;
    }
    lds[f][w * 4 + 0] = acc0;
    lds[f][w * 4 + 1] = acc1;
    lds[f][w * 4 + 2] = acc2;
    lds[f][w * 4 + 3] = acc3;
    __syncthreads();
    const int ff = threadIdx.x >> 2, q = threadIdx.x & 3;
    const int j0 = i0 + q * 4;
    const int jstep = j0 >> 5, off = j0 & 31;
    const int gg = off >> 3, e0 = off & 7;           // e0 in {0,4}
    const int m = ff >> 4, frl = ff & 15;
    short4 o;
    o.x = f2bf(lds[ff][q * 4 + 0]);
    o.y = f2bf(lds[ff][q * 4 + 1]);
    o.z = f2bf(lds[ff][q * 4 + 2]);
    o.w = f2bf(lds[ff][q * 4 + 3]);
    *(short4*)(Bp + ((size_t)(jstep * 4 + m) * 64 + gg * 16 + frl) * 8 + e0) = o;
}

// ---- Fused main: block = 64 rows x 1024 j; no LDS, no barriers ----
// Lane l: A-row = l&15, k-group g = l>>4. Per 128-j chunk: ONE int4 bitmap
// load per row; bits extracted to match A-fragment slots. B frags lane-linear
// from Bp (L2-resident); P@Wh via mfma_f32_16x16x32_bf16; den in f32.
__global__ __launch_bounds__(256) void gat_fused(const unsigned* __restrict__ bm,
    const float* __restrict__ fsrc, const float* __restrict__ fdst,
    const short* __restrict__ Bp, float* __restrict__ nump, float* __restrict__ denp)
{
    const int ib = blockIdx.x >> 3;           // / JSPLIT
    const int js = blockIdx.x & (JSPLIT - 1);
    const int i0 = ib * 64, jb = js * JSPAN;
    const int l = threadIdx.x & 63, w = threadIdx.x >> 6;
    const int rl = l & 15, g = l >> 4;
    const float fs = fsrc[i0 + w * 16 + rl];
    const uint4* brow = (const uint4*)(bm + (size_t)(i0 + w * 16 + rl) * PACKROW) + (jb >> 7);

    f32x4 acc0{0.f, 0.f, 0.f, 0.f}, acc1{0.f, 0.f, 0.f, 0.f};
    f32x4 acc2{0.f, 0.f, 0.f, 0.f}, acc3{0.f, 0.f, 0.f, 0.f};
    float den = 0.f;

    #pragma unroll 2
    for (int t = 0; t < JSPAN / 128; ++t) {
        const uint4 B4 = brow[t];
        #pragma unroll
        for (int s = 0; s < 4; ++s) {
            const int jg = jb + t * 128 + s * 32;
            const int jstep = jg >> 5;
            const short* bp = Bp + ((size_t)jstep * 4 * 64 + l) * 8;
            bf16x8 b0 = *(const bf16x8*)(bp);
            bf16x8 b1 = *(const bf16x8*)(bp + 1 * 64 * 8);
            bf16x8 b2 = *(const bf16x8*)(bp + 2 * 64 * 8);
            bf16x8 b3 = *(const bf16x8*)(bp + 3 * 64 * 8);
            const float* ep = fdst + jg + g * 8;
            float4 e0 = *(const float4*)ep;
            float4 e1 = *(const float4*)(ep + 4);
            const int sh = s * 8 + g * 2;
            const unsigned t0 = B4.x >> sh, t1 = B4.y >> sh;
            const unsigned t2 = B4.z >> sh, t3 = B4.w >> sh;
            // e = c + 4k: bit k of t_c
            float p0 = pbit(t0, 0, fs + e0.x);
            float p1 = pbit(t1, 0, fs + e0.y);
            float p2 = pbit(t2, 0, fs + e0.z);
            float p3 = pbit(t3, 0, fs + e0.w);
            float p4 = pbit(t0, 1, fs + e1.x);
            float p5 = pbit(t1, 1, fs + e1.y);
            float p6 = pbit(t2, 1, fs + e1.z);
            float p7 = pbit(t3, 1, fs + e1.w);
            den += ((p0 + p1) + (p2 + p3)) + ((p4 + p5) + (p6 + p7));
            bf16x8 af;
            af[0] = f2bf(p0); af[1] = f2bf(p1); af[2] = f2bf(p2); af[3] = f2bf(p3);
            af[4] = f2bf(p4); af[5] = f2bf(p5); af[6] = f2bf(p6); af[7] = f2bf(p7);
            acc0 = __builtin_amdgcn_mfma_f32_16x16x32_bf16(af, b0, acc0, 0, 0, 0);
            acc1 = __builtin_amdgcn_mfma_f32_16x16x32_bf16(af, b1, acc1, 0, 0, 0);
            acc2 = __builtin_amdgcn_mfma_f32_16x16x32_bf16(af, b2, acc2, 0, 0, 0);
            acc3 = __builtin_amdgcn_mfma_f32_16x16x32_bf16(af, b3, acc3, 0, 0, 0);
        }
    }

    den += __shfl_xor(den, 16);
    den += __shfl_xor(den, 32);
    if (l < 16) denp[(size_t)js * N + i0 + w * 16 + l] = den;
    // C/D layout: col = l&15, row = (l>>4)*4 + reg
    float* np = nump + (size_t)js * N * FOUT + (size_t)(i0 + w * 16) * FOUT;
    #pragma unroll
    for (int q = 0; q < 4; ++q) {
        const int orow = g * 4 + q;
        np[(size_t)orow * FOUT + 0  + rl] = acc0[q];
        np[(size_t)orow * FOUT + 16 + rl] = acc1[q];
        np[(size_t)orow * FOUT + 32 + rl] = acc2[q];
        np[(size_t)orow * FOUT + 48 + rl] = acc3[q];
    }
}

// ---- Pass C: out = elu(num/den) ----
__global__ __launch_bounds__(256) void gat_final(const float* __restrict__ nump,
    const float* __restrict__ denp, float* __restrict__ out)
{
    const int t = blockIdx.x * 256 + threadIdx.x;
    const int i = t >> 6;
    float num = 0.f, den = 0.f;
    for (int js = 0; js < JSPLIT; ++js) {
        num += nump[(size_t)js * N * FOUT + t];
        den += denp[(size_t)js * N + i];
    }
    const float x = num / den;
    out[t] = x > 0.f ? x : expm1f(x);
}

extern "C" void kernel_launch(void* const* d_in, const int* in_sizes, int n_in,
                              void* d_out, int out_size, void* d_ws, size_t ws_size,
                              hipStream_t stream) {
    const float* h   = (const float*)d_in[0];
    const int*   adj = (const int*)d_in[1];
    const float* W   = (const float*)d_in[2];
    const float* a   = (const float*)d_in[3];
    float* out = (float*)d_out;

    char* ws = (char*)d_ws;
    short* Bp   = (short*)ws;                             // 1 MiB
    float* fsrc = (float*)(ws + (size_t)(N / 32) * 4 * 64 * 8 * 2);
    float* fdst = fsrc + N;
    unsigned* bm = (unsigned*)(fdst + N);                 // N*PACKROW*4 ~ 8.5 MiB
    float* nump = (float*)((char*)bm + (size_t)N * PACKROW * 4);  // JSPLIT*2 MiB
    float* denp = nump + (size_t)JSPLIT * N * FOUT;       // JSPLIT*32 KiB

    gat_pack<<<2048, 256, 0, stream>>>(adj, bm);
    gat_prep<<<N / 16, 256, 0, stream>>>(h, W, a, Bp, fsrc, fdst);
    gat_fused<<<(N / 64) * JSPLIT, 256, 0, stream>>>(bm, fsrc, fdst, Bp, nump, denp);
    gat_final<<<(N * FOUT) / 256, 256, 0, stream>>>(nump, denp, out);
}

// Round 9
// 114.148 us; speedup vs baseline: 1.2259x; 1.2259x over previous
//
#include <hip/hip_runtime.h>

typedef __attribute__((ext_vector_type(8))) short bf16x8;
typedef __attribute__((ext_vector_type(4))) float f32x4;

#define N 8192
#define FIN 512
#define FOUT 64
#define JSPLIT 4
#define JSPAN 2048      // j per block
#define NCHUNK 16       // 128-j chunks per block
#define CHJ 128         // j per chunk
#define BUFB 32768      // LDS bytes per chunk buffer: 64 rows x 512 B

// round-to-nearest-even f32 -> bf16
static __device__ __forceinline__ short f2bf(float x) {
    unsigned u = __float_as_uint(x);
    u += 0x7FFFu + ((u >> 16) & 1u);
    return (short)(u >> 16);
}

// p = av>0 ? exp(leakyrelu(s, 0.2)) : 0
static __device__ __forceinline__ float pedge(int av, float s) {
    float p = __expf(fmaxf(s, 0.2f * s));
    return av > 0 ? p : 0.f;
}

// async global->LDS: dest = wave-uniform base + lane*16; src is PER-LANE.
// aux=2 -> NT (non-temporal): single-use stream, don't retain in caches.
static __device__ __forceinline__ void gload16nt(const void* g, void* l) {
    __builtin_amdgcn_global_load_lds(
        (const __attribute__((address_space(1))) void*)g,
        (__attribute__((address_space(3))) void*)l, 16, 0, 2);
}

// Pass A: Wh = h@W (f32 accum). Outputs:
//  Bp: MFMA-B fragments, lane-linear: Bp[((jstep*4 + m)*64 + (g*16+c))*8 + e]
//      = bf16(Wh[j = jstep*32 + g*8 + e][feat = m*16 + c])
//  fsrc, fdst: f32 [N], linear.
__global__ __launch_bounds__(256) void gat_prep(const float* __restrict__ h,
    const float* __restrict__ W, const float* __restrict__ a,
    short* __restrict__ Bp, float* __restrict__ fsrc, float* __restrict__ fdst)
{
    __shared__ float lds[FOUT][16];
    const int i0 = blockIdx.x * 16;
    const int w = threadIdx.x >> 6, f = threadIdx.x & 63;
    const int ir = i0 + w * 4;
    const float* h0 = h + (size_t)ir * FIN;
    float acc0 = 0.f, acc1 = 0.f, acc2 = 0.f, acc3 = 0.f;
    for (int k = 0; k < FIN; k += 4) {
        float wv0 = W[(k + 0) * FOUT + f];
        float wv1 = W[(k + 1) * FOUT + f];
        float wv2 = W[(k + 2) * FOUT + f];
        float wv3 = W[(k + 3) * FOUT + f];
        float4 h0v = *(const float4*)(h0 + k);
        float4 h1v = *(const float4*)(h0 + FIN + k);
        float4 h2v = *(const float4*)(h0 + 2 * FIN + k);
        float4 h3v = *(const float4*)(h0 + 3 * FIN + k);
        acc0 = fmaf(h0v.w, wv3, fmaf(h0v.z, wv2, fmaf(h0v.y, wv1, fmaf(h0v.x, wv0, acc0))));
        acc1 = fmaf(h1v.w, wv3, fmaf(h1v.z, wv2, fmaf(h1v.y, wv1, fmaf(h1v.x, wv0, acc1))));
        acc2 = fmaf(h2v.w, wv3, fmaf(h2v.z, wv2, fmaf(h2v.y, wv1, fmaf(h2v.x, wv0, acc2))));
        acc3 = fmaf(h3v.w, wv3, fmaf(h3v.z, wv2, fmaf(h3v.y, wv1, fmaf(h3v.x, wv0, acc3))));
    }
    const float as = a[f], ad = a[FOUT + f];
    float s0 = acc0 * as, s1 = acc1 * as, s2 = acc2 * as, s3 = acc3 * as;
    float d0 = acc0 * ad, d1 = acc1 * ad, d2 = acc2 * ad, d3 = acc3 * ad;
    #pragma unroll
    for (int m = 1; m < 64; m <<= 1) {
        s0 += __shfl_xor(s0, m); s1 += __shfl_xor(s1, m);
        s2 += __shfl_xor(s2, m); s3 += __shfl_xor(s3, m);
        d0 += __shfl_xor(d0, m); d1 += __shfl_xor(d1, m);
        d2 += __shfl_xor(d2, m); d3 += __shfl_xor(d3, m);
    }
    if (f == 0) {
        fsrc[ir + 0] = s0; fsrc[ir + 1] = s1; fsrc[ir + 2] = s2; fsrc[ir + 3] = s3;
        fdst[ir + 0] = d0; fdst[ir + 1] = d1; fdst[ir + 2] = d2; fdst[ir + 3] = d3;
    }
    lds[f][w * 4 + 0] = acc0;
    lds[f][w * 4 + 1] = acc1;
    lds[f][w * 4 + 2] = acc2;
    lds[f][w * 4 + 3] = acc3;
    __syncthreads();
    // write MFMA-B fragment layout: 4 consecutive j share (jstep, gg), e = 0..3/4..7
    const int ff = threadIdx.x >> 2, q = threadIdx.x & 3;
    const int j0 = i0 + q * 4;
    const int jstep = j0 >> 5, off = j0 & 31;
    const int gg = off >> 3, e0 = off & 7;           // e0 in {0,4}
    const int m = ff >> 4, frl = ff & 15;
    short4 o;
    o.x = f2bf(lds[ff][q * 4 + 0]);
    o.y = f2bf(lds[ff][q * 4 + 1]);
    o.z = f2bf(lds[ff][q * 4 + 2]);
    o.w = f2bf(lds[ff][q * 4 + 3]);
    *(short4*)(Bp + ((size_t)(jstep * 4 + m) * 64 + gg * 16 + frl) * 8 + e0) = o;
}

// Fused pass: block = 64 rows x 2048 j; 4 waves; wave w owns rows [w*16,+16).
// LDS is wave-private (each wave stages exactly the rows it computes) -> NO
// barriers. Per 128-j chunk: issue 24 register loads (B frags lane-linear from
// Bp + fdst), stage adj for chunk t+1 (8x NT gload16, 512 B contiguous per row
// x 2 rows, source pre-swizzled for bank-spread reads), counted
// s_waitcnt vmcnt(32) => chunk t's adj landed, then compute 4x 32-j MFMA steps.
__global__ __launch_bounds__(256, 2) void gat_fused(const int* __restrict__ adj,
    const float* __restrict__ fsrc, const float* __restrict__ fdst,
    const short* __restrict__ Bp, float* __restrict__ nump, float* __restrict__ denp)
{
    __shared__ int4 abuf4[2 * BUFB / 16];
    char* abuf = (char*)abuf4;
    const int ib = blockIdx.x / JSPLIT;
    const int js = blockIdx.x % JSPLIT;
    const int i0 = ib * 64, jb = js * JSPAN;
    const int l = threadIdx.x & 63, w = threadIdx.x >> 6;
    const int rl = l & 15, g = l >> 4;
    const float fs = fsrc[i0 + w * 16 + rl];

    f32x4 acc0{0.f, 0.f, 0.f, 0.f}, acc1{0.f, 0.f, 0.f, 0.f};
    f32x4 acc2{0.f, 0.f, 0.f, 0.f}, acc3{0.f, 0.f, 0.f, 0.f};
    float den = 0.f;
    bf16x8 Bv[4][4];
    float4 Ev[4][2];

    // staging: instr n covers local rows 2n,2n+1 (512 B contiguous each);
    // source 16B-unit pre-swizzled so LDS reads are bank-spread (G21).
    const char* adjw = (const char*)adj + ((size_t)(i0 + w * 16) * N + jb) * 4;
    const unsigned v = l & 31;
    const int rsub = l >> 5;

#define STAGE(t, buf) do {                                                     \
    const char* rb_ = adjw + (size_t)(t) * (CHJ * 4);                          \
    _Pragma("unroll")                                                          \
    for (int n_ = 0; n_ < 8; ++n_) {                                           \
        const int rs_ = 2 * n_ + rsub;                                         \
        const unsigned l16_ = (((v >> 1) ^ (unsigned)(rs_ & 15)) << 1) | (v & 1); \
        gload16nt(rb_ + (size_t)rs_ * (N * 4) + l16_ * 16,                     \
                  (buf) + (w * 16 + 2 * n_) * 512);                            \
    } } while (0)

#define ISSUE_REGS(t) do {                                                     \
    _Pragma("unroll")                                                          \
    for (int s_ = 0; s_ < 4; ++s_) {                                           \
        const int jstep_ = (jb >> 5) + (t) * 4 + s_;                           \
        const short* bp_ = Bp + ((size_t)jstep_ * 4 * 64 + l) * 8;             \
        _Pragma("unroll")                                                      \
        for (int m_ = 0; m_ < 4; ++m_)                                         \
            Bv[s_][m_] = *(const bf16x8*)(bp_ + (size_t)m_ * 64 * 8);          \
        const float* ep_ = fdst + jb + (t) * CHJ + s_ * 32 + g * 8;            \
        Ev[s_][0] = *(const float4*)ep_;                                       \
        Ev[s_][1] = *(const float4*)(ep_ + 4);                                 \
    } } while (0)

#define COMPUTE(buf) do {                                                      \
    const char* ar_ = (buf) + (w * 16 + rl) * 512;                             \
    _Pragma("unroll")                                                          \
    for (int s_ = 0; s_ < 4; ++s_) {                                           \
        const char* ap_ = ar_ + (((s_ * 4 + g) ^ rl) * 32);                    \
        int4 A0 = *(const int4*)ap_;                                           \
        int4 A1 = *(const int4*)(ap_ + 16);                                    \
        float p0 = pedge(A0.x, fs + Ev[s_][0].x);                              \
        float p1 = pedge(A0.y, fs + Ev[s_][0].y);                              \
        float p2 = pedge(A0.z, fs + Ev[s_][0].z);                              \
        float p3 = pedge(A0.w, fs + Ev[s_][0].w);                              \
        float p4 = pedge(A1.x, fs + Ev[s_][1].x);                              \
        float p5 = pedge(A1.y, fs + Ev[s_][1].y);                              \
        float p6 = pedge(A1.z, fs + Ev[s_][1].z);                              \
        float p7 = pedge(A1.w, fs + Ev[s_][1].w);                              \
        den += ((p0 + p1) + (p2 + p3)) + ((p4 + p5) + (p6 + p7));              \
        bf16x8 af;                                                             \
        af[0] = f2bf(p0); af[1] = f2bf(p1); af[2] = f2bf(p2); af[3] = f2bf(p3);\
        af[4] = f2bf(p4); af[5] = f2bf(p5); af[6] = f2bf(p6); af[7] = f2bf(p7);\
        acc0 = __builtin_amdgcn_mfma_f32_16x16x32_bf16(af, Bv[s_][0], acc0, 0, 0, 0); \
        acc1 = __builtin_amdgcn_mfma_f32_16x16x32_bf16(af, Bv[s_][1], acc1, 0, 0, 0); \
        acc2 = __builtin_amdgcn_mfma_f32_16x16x32_bf16(af, Bv[s_][2], acc2, 0, 0, 0); \
        acc3 = __builtin_amdgcn_mfma_f32_16x16x32_bf16(af, Bv[s_][3], acc3, 0, 0, 0); \
    } } while (0)

    STAGE(0, abuf);                                   // prologue
    for (int t = 0; t < NCHUNK - 1; ++t) {
        char* cb = abuf + (t & 1) * BUFB;
        char* nb = abuf + ((t + 1) & 1) * BUFB;
        ISSUE_REGS(t);                                // 24 register loads (older)
        STAGE(t + 1, nb);                             // 8 async LDS loads (newer)
        // in-order vmcnt: <=32 outstanding => chunk t's 8 adj loads retired;
        // compiler's own wait for Bv is vmcnt(8), keeping chunk t+1 in flight.
        asm volatile("s_waitcnt vmcnt(32)" ::: "memory");
        __builtin_amdgcn_sched_barrier(0);
        COMPUTE(cb);
    }
    {                                                 // peeled last chunk
        char* cb = abuf + ((NCHUNK - 1) & 1) * BUFB;
        ISSUE_REGS(NCHUNK - 1);
        asm volatile("s_waitcnt vmcnt(24)" ::: "memory");
        __builtin_amdgcn_sched_barrier(0);
        COMPUTE(cb);
    }
#undef STAGE
#undef ISSUE_REGS
#undef COMPUTE

    den += __shfl_xor(den, 16);
    den += __shfl_xor(den, 32);
    if (l < 16) denp[(size_t)js * N + i0 + w * 16 + l] = den;
    // C/D layout: col = l&15, row = (l>>4)*4 + reg
    float* np = nump + (size_t)js * N * FOUT + (size_t)(i0 + w * 16) * FOUT;
    #pragma unroll
    for (int q = 0; q < 4; ++q) {
        const int orow = g * 4 + q;
        np[(size_t)orow * FOUT + 0  + rl] = acc0[q];
        np[(size_t)orow * FOUT + 16 + rl] = acc1[q];
        np[(size_t)orow * FOUT + 32 + rl] = acc2[q];
        np[(size_t)orow * FOUT + 48 + rl] = acc3[q];
    }
}

// Pass C: out = elu(num/den)
__global__ __launch_bounds__(256) void gat_final(const float* __restrict__ nump,
    const float* __restrict__ denp, float* __restrict__ out)
{
    const int t = blockIdx.x * 256 + threadIdx.x;
    const int i = t >> 6;
    float num = 0.f, den = 0.f;
    for (int js = 0; js < JSPLIT; ++js) {
        num += nump[(size_t)js * N * FOUT + t];
        den += denp[(size_t)js * N + i];
    }
    const float x = num / den;
    out[t] = x > 0.f ? x : expm1f(x);
}

extern "C" void kernel_launch(void* const* d_in, const int* in_sizes, int n_in,
                              void* d_out, int out_size, void* d_ws, size_t ws_size,
                              hipStream_t stream) {
    const float* h   = (const float*)d_in[0];
    const int*   adj = (const int*)d_in[1];
    const float* W   = (const float*)d_in[2];
    const float* a   = (const float*)d_in[3];
    float* out = (float*)d_out;

    char* ws = (char*)d_ws;
    short* Bp   = (short*)ws;                            // (N/32)*4*64*8 shorts = 1 MiB
    float* fsrc = (float*)(ws + (size_t)(N / 32) * 4 * 64 * 8 * 2);
    float* fdst = fsrc + N;
    float* nump = fdst + N;                              // JSPLIT * 2 MiB
    float* denp = nump + (size_t)JSPLIT * N * FOUT;      // JSPLIT * 32 KiB

    gat_prep<<<N / 16, 256, 0, stream>>>(h, W, a, Bp, fsrc, fdst);
    gat_fused<<<(N / 64) * JSPLIT, 256, 0, stream>>>(adj, fsrc, fdst, Bp, nump, denp);
    gat_final<<<(N * FOUT) / 256, 256, 0, stream>>>(nump, denp, out);
}